// Round 10
// baseline (260.031 us; speedup 1.0000x reference)
//
#include <hip/hip_runtime.h>
#include <hip/hip_bf16.h>
#include <math.h>

#define SUMS 199
#define NBLK 1024   // 16 images = 4 batch elements per block, 512 threads

typedef __attribute__((ext_vector_type(8))) short short8;   // 8 bf16
typedef __attribute__((ext_vector_type(4))) float float4v;  // MFMA acc

union Frag8 { short8 v; unsigned u[4]; uint4 q; };

static __device__ inline unsigned pk_bf16(float a, float b) {
    __hip_bfloat162 h = __float22bfloat162_rn(make_float2(a, b));
    union { __hip_bfloat162 h; unsigned u; } c; c.h = h; return c.u;
}

// ---- pre-kernel: all weight fragments -> d_ws (bf16 frag layout) ----
__global__ __launch_bounds__(256) void convert_weights(
    const float* __restrict__ f1w, const float* __restrict__ f2w,
    const float* __restrict__ f3w, const float* __restrict__ c1w,
    const float* __restrict__ c2w, uint4* __restrict__ ws)
{
    const int g = blockIdx.x * 256 + threadIdx.x;
    if (g >= 6400) return;
    float v[8];
    if (g < 5824) {
        const float* W; int O, K, ld, nt, s, l;
        if (g < 4096)      { W = f1w; O = 120; K = 256; ld = 256; nt = g >> 9; s = (g >> 6) & 7; l = g & 63; }
        else if (g < 5632) { const int f = g - 4096; W = f2w; O = 84; K = 120; ld = 120; nt = f >> 8; s = (f >> 6) & 3; l = f & 63; }
        else               { const int f = g - 5632; W = f3w; O = 10; K = 84;  ld = 84;  nt = 0; s = f >> 6; l = f & 63; }
        const int o = nt * 16 + (l & 15);
        #pragma unroll
        for (int j = 0; j < 8; ++j) {
            const int k = 32 * s + 8 * (l >> 4) + j;
            v[j] = (o < O && k < K) ? W[o * ld + k] : 0.f;
        }
    } else if (g < 6336) {
        const int f = g - 5824, s = f >> 6, l = f & 63;
        const int c = l & 15, h = l >> 4;
        #pragma unroll
        for (int jp = 0; jp < 4; ++jp) {
            const int D = 16 * s + 4 * h + jp;
            const int ky = D / 24, rem = D % 24, kx = rem >> 2, icp = rem & 3;
            const bool ok = (ky < 5 && kx < 5);
            v[2 * jp]     = (ok && 2 * icp < 6)     ? c2w[c * 150 + (2 * icp) * 25 + ky * 5 + kx]     : 0.f;
            v[2 * jp + 1] = (ok && 2 * icp + 1 < 6) ? c2w[c * 150 + (2 * icp + 1) * 25 + ky * 5 + kx] : 0.f;
        }
    } else {
        const int l = (g - 6336) & 63;
        const int c = l & 15, h = l >> 4;
        const int oc = c >> 1, xs = c & 1;
        #pragma unroll
        for (int j = 0; j < 8; ++j) {
            const int p = h * 4 + (j >> 1);
            float w = 0.f;
            if (p < 15 && c < 12) {
                const int ky = p / 3, kx = 2 * (p % 3) + (j & 1) - xs;
                if (kx >= 0 && kx < 5) w = c1w[oc * 25 + ky * 5 + kx];
            }
            v[j] = w;
        }
    }
    uint4 r;
    r.x = pk_bf16(v[0], v[1]); r.y = pk_bf16(v[2], v[3]);
    r.z = pk_bf16(v[4], v[5]); r.w = pk_bf16(v[6], v[7]);
    ws[g] = r;
}

// LDS map (39712 B -> 4 blocks/CU x 8 waves = 32 waves/CU):
//  [0,12576)      imgu bf16 [8][393 dw] per pass; after convs: A2 [16][68dw]@0,
//                 A3 [16][52dw]@4352, lgf [16][12]f32 @7680
//  [12576,31264)  p1 bf16 [8][12][12][8ic] + tail (zeroed; R5 lesson); after
//                 last conv2: E1P[4ph][4be][104] @12576, E2RP @19232 (zero-pad
//                 phase-shifted copies for aligned float4 segment dots)
//  [31264,39712)  A1 bf16 [16 img][132 dw]
__global__ __launch_bounds__(512, 8) void lenet_circuit_kernel(
    const float* __restrict__ images,
    const float* __restrict__ c1b, const float* __restrict__ c2b,
    const float* __restrict__ f1b, const float* __restrict__ f2b,
    const float* __restrict__ f3b, const uint4* __restrict__ wsb,
    float* __restrict__ out)
{
    __shared__ __align__(16) unsigned char s_mem[39712];
    unsigned*       imgu = (unsigned*)s_mem;
    unsigned short* p1s  = (unsigned short*)(s_mem + 12576);
    const uint4*    p1u4 = (const uint4*)(s_mem + 12576);
    unsigned*       A1d  = (unsigned*)(s_mem + 31264);
    const uint4*    A1q  = (const uint4*)(s_mem + 31264);
    float*          E1Pf = (float*)(s_mem + 12576);   // [4ph][4be][104]
    float*          E2Rf = (float*)(s_mem + 19232);   // [4ph][4be][104]

    const int t = threadIdx.x, bid = blockIdx.x;
    const int lane = t & 63, wav = t >> 6;   // 8 waves
    const int c = lane & 15, h = lane >> 4;
    const uint4 z4 = {0u, 0u, 0u, 0u};

    // ---- zero p1 region once ----
    {
        uint4* pz = (uint4*)(s_mem + 12576);
        for (int i = t; i < 1168; i += 512) pz[i] = z4;
    }
    // ---- load weight fragments (coalesced) ----
    Frag8 a1; a1.q = wsb[6336 + lane];
    Frag8 w2[8];
    #pragma unroll
    for (int s = 0; s < 8; ++s) w2[s].q = wsb[5824 + s * 64 + lane];
    int koff[8];
    #pragma unroll
    for (int s = 0; s < 8; ++s) {
        const int D0 = 16 * s + 4 * h;
        koff[s] = (D0 / 24) * 12 + ((D0 % 24) >> 2);
    }
    int pd[4];
    #pragma unroll
    for (int q = 0; q < 4; ++q) {
        const int p = 4 * h + q;
        pd[q] = (p < 15) ? (p / 3) * 14 + (p % 3) : 0;
    }
    float bias0 = 0.f, bias1 = 0.f;
    if (h < 3) { bias0 = c1b[2 * h]; bias1 = c1b[2 * h + 1]; }
    const float b2v = c2b[c];

    // ================= two conv passes (8 images each) =================
    for (int pass = 0; pass < 2; ++pass) {
        // ---- stage 8 images fp32 -> bf16 ----
        {
            const float4* g = (const float4*)(images + (size_t)bid * 12544 + pass * 6272);
            for (int i = t; i < 1568; i += 512) {
                const float4 v = g[i];
                const int im = i / 196, j = i % 196;
                imgu[im * 393 + 2 * j]     = pk_bf16(v.x, v.y);
                imgu[im * 393 + 2 * j + 1] = pk_bf16(v.z, v.w);
            }
        }
        __syncthreads();

        // ---- conv1: 18 MFMA-tasks per wave ----
        {
            const int n = c, img = n >> 1;
            const int imb = img * 393 + (n & 1) * 14;
            for (int task = wav * 18; task < wav * 18 + 18; ++task) {
                const int qy = task / 12, qx = task % 12;
                const int base = imb + qy * 28 + qx;
                Frag8 bf;
                #pragma unroll
                for (int q = 0; q < 4; ++q) bf.u[q] = imgu[base + pd[q]];
                float4v acc = {0.f, 0.f, 0.f, 0.f};
                acc = __builtin_amdgcn_mfma_f32_16x16x32_bf16(a1.v, bf.v, acc, 0, 0, 0);
                float v0 = fmaxf(acc[0], acc[1]);
                float v1 = fmaxf(acc[2], acc[3]);
                v0 = fmaxf(v0, __shfl_xor(v0, 1));
                v1 = fmaxf(v1, __shfl_xor(v1, 1));
                if ((n & 1) == 0 && h < 3) {
                    const unsigned pkv = pk_bf16(fmaxf(v0 + bias0, 0.f),
                                                 fmaxf(v1 + bias1, 0.f));
                    *(unsigned*)&p1s[img * 1152 + qy * 96 + qx * 8 + 2 * h] = pkv;
                }
            }
        }
        __syncthreads();

        // ---- conv2: wave = image i0; 32 MFMA/wave ----
        {
            const int i0 = wav;
            const int pxl = (c & 1) + 2 * ((c >> 2) & 1);
            const int pyl = ((c >> 1) & 1) + 2 * ((c >> 3) & 1);
            #pragma unroll
            for (int mt = 0; mt < 4; ++mt) {
                const int px = pxl + 4 * (mt & 1), py = pyl + 4 * (mt >> 1);
                const int base = i0 * 144 + py * 12 + px;
                float4v acc = {0.f, 0.f, 0.f, 0.f};
                #pragma unroll
                for (int s = 0; s < 8; ++s) {
                    Frag8 af; af.q = p1u4[base + koff[s]];
                    acc = __builtin_amdgcn_mfma_f32_16x16x32_bf16(af.v, w2[s].v, acc, 0, 0, 0);
                }
                const float p = fmaxf(fmaxf(acc[0], acc[1]), fmaxf(acc[2], acc[3]));
                float v = fmaxf(p + b2v, 0.f);
                const float vp = __shfl_xor(v, 16);
                if ((h & 1) == 0) {
                    const int qy = (h >> 1) + 2 * (mt >> 1);
                    A1d[(pass * 8 + i0) * 132 + c * 8 + qy * 2 + (mt & 1)] = pk_bf16(v, vp);
                }
            }
        }
    }
    __syncthreads();   // A1 complete; p1 dead

    // ---- fc1 via MFMA (nt = wav, 8 MFMA/wave) + zero phase region ----
    {
        uint4* pz = (uint4*)(s_mem + 12576);        // zero E1P+E2RP (13312 B)
        for (int i = t; i < 832; i += 512) pz[i] = z4;
        unsigned* A2d = (unsigned*)s_mem;
        if (t < 64) A2d[(t >> 2) * 68 + 60 + (t & 3)] = 0u;   // k-pad 120-127
        float4v acc = {0.f, 0.f, 0.f, 0.f};
        #pragma unroll
        for (int s = 0; s < 8; ++s) {
            Frag8 af; af.q = A1q[c * 33 + 4 * s + h];
            Frag8 b; b.q = wsb[(wav * 8 + s) * 64 + lane];
            acc = __builtin_amdgcn_mfma_f32_16x16x32_bf16(af.v, b.v, acc, 0, 0, 0);
        }
        const int o = 16 * wav + c;
        const float bias = (o < 120) ? f1b[o] : 0.f;
        #pragma unroll
        for (int r = 0; r < 4; ++r) {
            float v = fmaxf(acc[r] + bias, 0.f);
            const float vp = __shfl_xor(v, 1);
            if ((c & 1) == 0 && o < 120)
                A2d[(4 * h + r) * 68 + (o >> 1)] = pk_bf16(v, vp);
        }
    }
    __syncthreads();

    // ---- fc2 via MFMA (waves 0-5, 4 MFMA each) ----
    {
        unsigned* A3d = (unsigned*)(s_mem + 4352);
        if (t < 96) A3d[(t / 6) * 52 + 42 + (t % 6)] = 0u;    // k-pad 84-95
        if (wav < 6) {
            const uint4* A2q = (const uint4*)s_mem;
            float4v acc = {0.f, 0.f, 0.f, 0.f};
            #pragma unroll
            for (int s = 0; s < 4; ++s) {
                Frag8 af; af.q = A2q[c * 17 + 4 * s + h];
                Frag8 b; b.q = wsb[4096 + (wav * 4 + s) * 64 + lane];
                acc = __builtin_amdgcn_mfma_f32_16x16x32_bf16(af.v, b.v, acc, 0, 0, 0);
            }
            const int o = 16 * wav + c;
            const float bias = (o < 84) ? f2b[o] : 0.f;
            #pragma unroll
            for (int r = 0; r < 4; ++r) {
                float v = fmaxf(acc[r] + bias, 0.f);
                const float vp = __shfl_xor(v, 1);
                if ((c & 1) == 0 && o < 84)
                    A3d[(4 * h + r) * 52 + (o >> 1)] = pk_bf16(v, vp);
            }
        }
    }
    __syncthreads();

    float* lgf = (float*)(s_mem + 7680);    // [16][12]

    // ---- fc3 via MFMA (wave 0) ----
    if (wav == 0) {
        const uint4* A3q = (const uint4*)(s_mem + 4352);
        float4v acc = {0.f, 0.f, 0.f, 0.f};
        #pragma unroll
        for (int s = 0; s < 3; ++s) {
            Frag8 af; af.q = A3q[c * 13 + 4 * s + h];
            Frag8 b; b.q = wsb[5632 + s * 64 + lane];
            acc = __builtin_amdgcn_mfma_f32_16x16x32_bf16(af.v, b.v, acc, 0, 0, 0);
        }
        if (c < 10) {
            const float bias = f3b[c];
            #pragma unroll
            for (int r = 0; r < 4; ++r) lgf[(4 * h + r) * 12 + c] = acc[r] + bias;
        }
    }
    __syncthreads();

    // ---- log_softmax per image (16) ----
    if (t < 16) {
        float* lp = lgf + t * 12;
        float mx = -INFINITY;
        #pragma unroll
        for (int i = 0; i < 10; ++i) mx = fmaxf(mx, lp[i]);
        float sum = 0.f;
        #pragma unroll
        for (int i = 0; i < 10; ++i) sum += expf(lp[i] - mx);
        const float lse = mx + logf(sum);
        #pragma unroll
        for (int i = 0; i < 10; ++i) lp[i] -= lse;
    }
    __syncthreads();

    // ---- per-number probs -> 4 phase-shifted copies (E2 stored reversed) ----
    for (int idx = t; idx < 800; idx += 512) {
        const int be = idx / 200, r = idx % 200;
        const float* lp = lgf + 4 * be * 12;
        if (r < 100) {
            const float v = expf(lp[r / 10] + lp[12 + r % 10]);
            #pragma unroll
            for (int ph = 0; ph < 4; ++ph)
                E1Pf[(ph * 4 + be) * 104 + r + ph] = v;
        } else {
            const int k = r - 100;
            const float v = expf(lp[24 + k / 10] + lp[36 + k % 10]);
            #pragma unroll
            for (int ph = 0; ph < 4; ++ph)
                E2Rf[(ph * 4 + be) * 104 + (99 - k) + ph] = v;
        }
    }
    __syncthreads();

    // ---- segments: thread t<400 owns pair (sp, sp+99); aligned float4 dots ----
    if (t < 400) {
        const int be = t / 100, sp = t % 100;
        float* ob = out + ((size_t)bid * 4 + be) * SUMS;
        // form1: sum_{i=0..sp} E1[i]*E2r[99-sp+i]  -> ob[sp]
        // form2: sum_{j=0..99-sp} E1[sp+j]*E2r[j]  -> ob[sp+99]  (sp>=1)
        #pragma unroll
        for (int form = 0; form < 2; ++form) {
            const int o1 = form ? sp : 0;
            const int o2 = form ? 0 : 99 - sp;
            const int len = form ? 100 - sp : sp + 1;
            if (form && sp == 0) break;
            const int ph1 = (4 - (o1 & 3)) & 3, ph2 = (4 - (o2 & 3)) & 3;
            const float4* P1 = (const float4*)(E1Pf + (ph1 * 4 + be) * 104) + ((o1 + ph1) >> 2);
            const float4* P2 = (const float4*)(E2Rf + (ph2 * 4 + be) * 104) + ((o2 + ph2) >> 2);
            const int nv = (len + 3) >> 2;
            float s = 0.f;
            for (int j = 0; j < nv; ++j) {
                const float4 a = P1[j], b = P2[j];
                s += a.x * b.x + a.y * b.y + a.z * b.z + a.w * b.w;
            }
            ob[form ? sp + 99 : sp] = logf(s);
        }
    }
}

extern "C" void kernel_launch(void* const* d_in, const int* in_sizes, int n_in,
                              void* d_out, int out_size, void* d_ws, size_t ws_size,
                              hipStream_t stream) {
    const float* images = (const float*)d_in[0];
    const float* c1w = (const float*)d_in[1];
    const float* c1b = (const float*)d_in[2];
    const float* c2w = (const float*)d_in[3];
    const float* c2b = (const float*)d_in[4];
    const float* f1w = (const float*)d_in[5];
    const float* f1b = (const float*)d_in[6];
    const float* f2w = (const float*)d_in[7];
    const float* f2b = (const float*)d_in[8];
    const float* f3w = (const float*)d_in[9];
    const float* f3b = (const float*)d_in[10];
    float* out = (float*)d_out;

    convert_weights<<<25, 256, 0, stream>>>(f1w, f2w, f3w, c1w, c2w, (uint4*)d_ws);
    lenet_circuit_kernel<<<NBLK, 512, 0, stream>>>(
        images, c1b, c2b, f1b, f2b, f3b, (const uint4*)d_ws, out);
}

// Round 11
// 208.086 us; speedup vs baseline: 1.2496x; 1.2496x over previous
//
#include <hip/hip_runtime.h>
#include <hip/hip_bf16.h>
#include <math.h>

#define SUMS 199
#define NBLK 1024   // 16 images = 4 batch elements per block, 512 threads

typedef __attribute__((ext_vector_type(8))) short short8;   // 8 bf16
typedef __attribute__((ext_vector_type(4))) float float4v;  // MFMA acc

union Frag8 { short8 v; unsigned u[4]; uint4 q; };

static __device__ inline unsigned pk_bf16(float a, float b) {
    __hip_bfloat162 h = __float22bfloat162_rn(make_float2(a, b));
    union { __hip_bfloat162 h; unsigned u; } c; c.h = h; return c.u;
}

// ---- pre-kernel: all weight fragments -> d_ws (bf16 frag layout) ----
__global__ __launch_bounds__(256) void convert_weights(
    const float* __restrict__ f1w, const float* __restrict__ f2w,
    const float* __restrict__ f3w, const float* __restrict__ c1w,
    const float* __restrict__ c2w, uint4* __restrict__ ws)
{
    const int g = blockIdx.x * 256 + threadIdx.x;
    if (g >= 6400) return;
    float v[8];
    if (g < 5824) {
        const float* W; int O, K, ld, nt, s, l;
        if (g < 4096)      { W = f1w; O = 120; K = 256; ld = 256; nt = g >> 9; s = (g >> 6) & 7; l = g & 63; }
        else if (g < 5632) { const int f = g - 4096; W = f2w; O = 84; K = 120; ld = 120; nt = f >> 8; s = (f >> 6) & 3; l = f & 63; }
        else               { const int f = g - 5632; W = f3w; O = 10; K = 84;  ld = 84;  nt = 0; s = f >> 6; l = f & 63; }
        const int o = nt * 16 + (l & 15);
        #pragma unroll
        for (int j = 0; j < 8; ++j) {
            const int k = 32 * s + 8 * (l >> 4) + j;
            v[j] = (o < O && k < K) ? W[o * ld + k] : 0.f;
        }
    } else if (g < 6336) {
        const int f = g - 5824, s = f >> 6, l = f & 63;
        const int c = l & 15, h = l >> 4;
        #pragma unroll
        for (int jp = 0; jp < 4; ++jp) {
            const int D = 16 * s + 4 * h + jp;
            const int ky = D / 24, rem = D % 24, kx = rem >> 2, icp = rem & 3;
            const bool ok = (ky < 5 && kx < 5);
            v[2 * jp]     = (ok && 2 * icp < 6)     ? c2w[c * 150 + (2 * icp) * 25 + ky * 5 + kx]     : 0.f;
            v[2 * jp + 1] = (ok && 2 * icp + 1 < 6) ? c2w[c * 150 + (2 * icp + 1) * 25 + ky * 5 + kx] : 0.f;
        }
    } else {
        const int l = (g - 6336) & 63;
        const int c = l & 15, h = l >> 4;
        const int oc = c >> 1, xs = c & 1;
        #pragma unroll
        for (int j = 0; j < 8; ++j) {
            const int p = h * 4 + (j >> 1);
            float w = 0.f;
            if (p < 15 && c < 12) {
                const int ky = p / 3, kx = 2 * (p % 3) + (j & 1) - xs;
                if (kx >= 0 && kx < 5) w = c1w[oc * 25 + ky * 5 + kx];
            }
            v[j] = w;
        }
    }
    uint4 r;
    r.x = pk_bf16(v[0], v[1]); r.y = pk_bf16(v[2], v[3]);
    r.z = pk_bf16(v[4], v[5]); r.w = pk_bf16(v[6], v[7]);
    ws[g] = r;
}

// LDS map (39712 B -> 4 blocks/CU x 8 waves = 32 waves/CU):
//  [0,12576)      imgu bf16 [8][393 dw] per pass; after convs: A2 [16][68dw]@0,
//                 A3 [16][52dw]@4352, lgf [16][12]f32 @7680
//  [12576,31264)  p1 bf16 [8][12][12][8ic] + tail (zeroed; R5 lesson); after
//                 last conv2: E1P[4ph][4be][104] @12576, E2RP @19232 (zero-pad
//                 phase-shifted copies for aligned float4 segment dots)
//  [31264,39712)  A1 bf16 [16 img][132 dw]
// NOTE __launch_bounds__ 2nd arg acts as min BLOCKS/CU here (R10 evidence:
// (512,8) -> VGPR forced to 32 -> 253 MB scratch spill). (512,4) => VGPR<=64.
__global__ __launch_bounds__(512, 4) void lenet_circuit_kernel(
    const float* __restrict__ images,
    const float* __restrict__ c1b, const float* __restrict__ c2b,
    const float* __restrict__ f1b, const float* __restrict__ f2b,
    const float* __restrict__ f3b, const uint4* __restrict__ wsb,
    float* __restrict__ out)
{
    __shared__ __align__(16) unsigned char s_mem[39712];
    unsigned*       imgu = (unsigned*)s_mem;
    unsigned short* p1s  = (unsigned short*)(s_mem + 12576);
    const uint4*    p1u4 = (const uint4*)(s_mem + 12576);
    unsigned*       A1d  = (unsigned*)(s_mem + 31264);
    const uint4*    A1q  = (const uint4*)(s_mem + 31264);
    float*          E1Pf = (float*)(s_mem + 12576);   // [4ph][4be][104]
    float*          E2Rf = (float*)(s_mem + 19232);   // [4ph][4be][104]

    const int t = threadIdx.x, bid = blockIdx.x;
    const int lane = t & 63, wav = t >> 6;   // 8 waves
    const int c = lane & 15, h = lane >> 4;
    const uint4 z4 = {0u, 0u, 0u, 0u};

    // ---- zero p1 region once ----
    {
        uint4* pz = (uint4*)(s_mem + 12576);
        for (int i = t; i < 1168; i += 512) pz[i] = z4;
    }
    // ---- load weight fragments (coalesced) ----
    Frag8 a1; a1.q = wsb[6336 + lane];
    Frag8 w2[8];
    #pragma unroll
    for (int s = 0; s < 8; ++s) w2[s].q = wsb[5824 + s * 64 + lane];
    int koff[8];
    #pragma unroll
    for (int s = 0; s < 8; ++s) {
        const int D0 = 16 * s + 4 * h;
        koff[s] = (D0 / 24) * 12 + ((D0 % 24) >> 2);
    }
    int pd[4];
    #pragma unroll
    for (int q = 0; q < 4; ++q) {
        const int p = 4 * h + q;
        pd[q] = (p < 15) ? (p / 3) * 14 + (p % 3) : 0;
    }
    float bias0 = 0.f, bias1 = 0.f;
    if (h < 3) { bias0 = c1b[2 * h]; bias1 = c1b[2 * h + 1]; }
    const float b2v = c2b[c];

    // ================= two conv passes (8 images each) =================
    for (int pass = 0; pass < 2; ++pass) {
        // ---- stage 8 images fp32 -> bf16 ----
        {
            const float4* g = (const float4*)(images + (size_t)bid * 12544 + pass * 6272);
            for (int i = t; i < 1568; i += 512) {
                const float4 v = g[i];
                const int im = i / 196, j = i % 196;
                imgu[im * 393 + 2 * j]     = pk_bf16(v.x, v.y);
                imgu[im * 393 + 2 * j + 1] = pk_bf16(v.z, v.w);
            }
        }
        __syncthreads();

        // ---- conv1: 18 MFMA-tasks per wave ----
        {
            const int n = c, img = n >> 1;
            const int imb = img * 393 + (n & 1) * 14;
            for (int task = wav * 18; task < wav * 18 + 18; ++task) {
                const int qy = task / 12, qx = task % 12;
                const int base = imb + qy * 28 + qx;
                Frag8 bf;
                #pragma unroll
                for (int q = 0; q < 4; ++q) bf.u[q] = imgu[base + pd[q]];
                float4v acc = {0.f, 0.f, 0.f, 0.f};
                acc = __builtin_amdgcn_mfma_f32_16x16x32_bf16(a1.v, bf.v, acc, 0, 0, 0);
                float v0 = fmaxf(acc[0], acc[1]);
                float v1 = fmaxf(acc[2], acc[3]);
                v0 = fmaxf(v0, __shfl_xor(v0, 1));
                v1 = fmaxf(v1, __shfl_xor(v1, 1));
                if ((n & 1) == 0 && h < 3) {
                    const unsigned pkv = pk_bf16(fmaxf(v0 + bias0, 0.f),
                                                 fmaxf(v1 + bias1, 0.f));
                    *(unsigned*)&p1s[img * 1152 + qy * 96 + qx * 8 + 2 * h] = pkv;
                }
            }
        }
        __syncthreads();

        // ---- conv2: wave = image i0; 32 MFMA/wave ----
        {
            const int i0 = wav;
            const int pxl = (c & 1) + 2 * ((c >> 2) & 1);
            const int pyl = ((c >> 1) & 1) + 2 * ((c >> 3) & 1);
            #pragma unroll
            for (int mt = 0; mt < 4; ++mt) {
                const int px = pxl + 4 * (mt & 1), py = pyl + 4 * (mt >> 1);
                const int base = i0 * 144 + py * 12 + px;
                float4v acc = {0.f, 0.f, 0.f, 0.f};
                #pragma unroll
                for (int s = 0; s < 8; ++s) {
                    Frag8 af; af.q = p1u4[base + koff[s]];
                    acc = __builtin_amdgcn_mfma_f32_16x16x32_bf16(af.v, w2[s].v, acc, 0, 0, 0);
                }
                const float p = fmaxf(fmaxf(acc[0], acc[1]), fmaxf(acc[2], acc[3]));
                float v = fmaxf(p + b2v, 0.f);
                const float vp = __shfl_xor(v, 16);
                if ((h & 1) == 0) {
                    const int qy = (h >> 1) + 2 * (mt >> 1);
                    A1d[(pass * 8 + i0) * 132 + c * 8 + qy * 2 + (mt & 1)] = pk_bf16(v, vp);
                }
            }
        }
    }
    __syncthreads();   // A1 complete; p1 dead

    // ---- fc1 via MFMA (nt = wav, 8 MFMA/wave) + zero phase region ----
    {
        uint4* pz = (uint4*)(s_mem + 12576);        // zero E1P+E2RP (13312 B)
        for (int i = t; i < 832; i += 512) pz[i] = z4;
        unsigned* A2d = (unsigned*)s_mem;
        if (t < 64) A2d[(t >> 2) * 68 + 60 + (t & 3)] = 0u;   // k-pad 120-127
        float4v acc = {0.f, 0.f, 0.f, 0.f};
        #pragma unroll
        for (int s = 0; s < 8; ++s) {
            Frag8 af; af.q = A1q[c * 33 + 4 * s + h];
            Frag8 b; b.q = wsb[(wav * 8 + s) * 64 + lane];
            acc = __builtin_amdgcn_mfma_f32_16x16x32_bf16(af.v, b.v, acc, 0, 0, 0);
        }
        const int o = 16 * wav + c;
        const float bias = (o < 120) ? f1b[o] : 0.f;
        #pragma unroll
        for (int r = 0; r < 4; ++r) {
            float v = fmaxf(acc[r] + bias, 0.f);
            const float vp = __shfl_xor(v, 1);
            if ((c & 1) == 0 && o < 120)
                A2d[(4 * h + r) * 68 + (o >> 1)] = pk_bf16(v, vp);
        }
    }
    __syncthreads();

    // ---- fc2 via MFMA (waves 0-5, 4 MFMA each) ----
    {
        unsigned* A3d = (unsigned*)(s_mem + 4352);
        if (t < 96) A3d[(t / 6) * 52 + 42 + (t % 6)] = 0u;    // k-pad 84-95
        if (wav < 6) {
            const uint4* A2q = (const uint4*)s_mem;
            float4v acc = {0.f, 0.f, 0.f, 0.f};
            #pragma unroll
            for (int s = 0; s < 4; ++s) {
                Frag8 af; af.q = A2q[c * 17 + 4 * s + h];
                Frag8 b; b.q = wsb[4096 + (wav * 4 + s) * 64 + lane];
                acc = __builtin_amdgcn_mfma_f32_16x16x32_bf16(af.v, b.v, acc, 0, 0, 0);
            }
            const int o = 16 * wav + c;
            const float bias = (o < 84) ? f2b[o] : 0.f;
            #pragma unroll
            for (int r = 0; r < 4; ++r) {
                float v = fmaxf(acc[r] + bias, 0.f);
                const float vp = __shfl_xor(v, 1);
                if ((c & 1) == 0 && o < 84)
                    A3d[(4 * h + r) * 52 + (o >> 1)] = pk_bf16(v, vp);
            }
        }
    }
    __syncthreads();

    float* lgf = (float*)(s_mem + 7680);    // [16][12]

    // ---- fc3 via MFMA (wave 0) ----
    if (wav == 0) {
        const uint4* A3q = (const uint4*)(s_mem + 4352);
        float4v acc = {0.f, 0.f, 0.f, 0.f};
        #pragma unroll
        for (int s = 0; s < 3; ++s) {
            Frag8 af; af.q = A3q[c * 13 + 4 * s + h];
            Frag8 b; b.q = wsb[5632 + s * 64 + lane];
            acc = __builtin_amdgcn_mfma_f32_16x16x32_bf16(af.v, b.v, acc, 0, 0, 0);
        }
        if (c < 10) {
            const float bias = f3b[c];
            #pragma unroll
            for (int r = 0; r < 4; ++r) lgf[(4 * h + r) * 12 + c] = acc[r] + bias;
        }
    }
    __syncthreads();

    // ---- log_softmax per image (16) ----
    if (t < 16) {
        float* lp = lgf + t * 12;
        float mx = -INFINITY;
        #pragma unroll
        for (int i = 0; i < 10; ++i) mx = fmaxf(mx, lp[i]);
        float sum = 0.f;
        #pragma unroll
        for (int i = 0; i < 10; ++i) sum += expf(lp[i] - mx);
        const float lse = mx + logf(sum);
        #pragma unroll
        for (int i = 0; i < 10; ++i) lp[i] -= lse;
    }
    __syncthreads();

    // ---- per-number probs -> 4 phase-shifted copies (E2 stored reversed) ----
    for (int idx = t; idx < 800; idx += 512) {
        const int be = idx / 200, r = idx % 200;
        const float* lp = lgf + 4 * be * 12;
        if (r < 100) {
            const float v = expf(lp[r / 10] + lp[12 + r % 10]);
            #pragma unroll
            for (int ph = 0; ph < 4; ++ph)
                E1Pf[(ph * 4 + be) * 104 + r + ph] = v;
        } else {
            const int k = r - 100;
            const float v = expf(lp[24 + k / 10] + lp[36 + k % 10]);
            #pragma unroll
            for (int ph = 0; ph < 4; ++ph)
                E2Rf[(ph * 4 + be) * 104 + (99 - k) + ph] = v;
        }
    }
    __syncthreads();

    // ---- segments: thread t<400 owns pair (sp, sp+99); aligned float4 dots ----
    if (t < 400) {
        const int be = t / 100, sp = t % 100;
        float* ob = out + ((size_t)bid * 4 + be) * SUMS;
        // form1: sum_{i=0..sp} E1[i]*E2r[99-sp+i]  -> ob[sp]
        // form2: sum_{j=0..99-sp} E1[sp+j]*E2r[j]  -> ob[sp+99]  (sp>=1)
        #pragma unroll
        for (int form = 0; form < 2; ++form) {
            const int o1 = form ? sp : 0;
            const int o2 = form ? 0 : 99 - sp;
            const int len = form ? 100 - sp : sp + 1;
            if (form && sp == 0) break;
            const int ph1 = (4 - (o1 & 3)) & 3, ph2 = (4 - (o2 & 3)) & 3;
            const float4* P1 = (const float4*)(E1Pf + (ph1 * 4 + be) * 104) + ((o1 + ph1) >> 2);
            const float4* P2 = (const float4*)(E2Rf + (ph2 * 4 + be) * 104) + ((o2 + ph2) >> 2);
            const int nv = (len + 3) >> 2;
            float s = 0.f;
            for (int j = 0; j < nv; ++j) {
                const float4 a = P1[j], b = P2[j];
                s += a.x * b.x + a.y * b.y + a.z * b.z + a.w * b.w;
            }
            ob[form ? sp + 99 : sp] = logf(s);
        }
    }
}

extern "C" void kernel_launch(void* const* d_in, const int* in_sizes, int n_in,
                              void* d_out, int out_size, void* d_ws, size_t ws_size,
                              hipStream_t stream) {
    const float* images = (const float*)d_in[0];
    const float* c1w = (const float*)d_in[1];
    const float* c1b = (const float*)d_in[2];
    const float* c2w = (const float*)d_in[3];
    const float* c2b = (const float*)d_in[4];
    const float* f1w = (const float*)d_in[5];
    const float* f1b = (const float*)d_in[6];
    const float* f2w = (const float*)d_in[7];
    const float* f2b = (const float*)d_in[8];
    const float* f3w = (const float*)d_in[9];
    const float* f3b = (const float*)d_in[10];
    float* out = (float*)d_out;

    convert_weights<<<25, 256, 0, stream>>>(f1w, f2w, f3w, c1w, c2w, (uint4*)d_ws);
    lenet_circuit_kernel<<<NBLK, 512, 0, stream>>>(
        images, c1b, c2b, f1b, f2b, f3b, (const uint4*)d_ws, out);
}

// Round 12
// 176.075 us; speedup vs baseline: 1.4768x; 1.1818x over previous
//
#include <hip/hip_runtime.h>
#include <hip/hip_bf16.h>
#include <math.h>

#define SUMS 199
#define NBLK 1024   // 16 images = 4 batch elements per block, 512 threads

typedef __attribute__((ext_vector_type(8))) short short8;   // 8 bf16
typedef __attribute__((ext_vector_type(4))) float float4v;  // MFMA acc

union Frag8 { short8 v; unsigned u[4]; uint4 q; };

static __device__ inline unsigned pk_bf16(float a, float b) {
    __hip_bfloat162 h = __float22bfloat162_rn(make_float2(a, b));
    union { __hip_bfloat162 h; unsigned u; } c; c.h = h; return c.u;
}

// ---- pre-kernel: all weight fragments -> d_ws (bf16 frag layout) ----
__global__ __launch_bounds__(256) void convert_weights(
    const float* __restrict__ f1w, const float* __restrict__ f2w,
    const float* __restrict__ f3w, const float* __restrict__ c1w,
    const float* __restrict__ c2w, uint4* __restrict__ ws)
{
    const int g = blockIdx.x * 256 + threadIdx.x;
    if (g >= 6400) return;
    float v[8];
    if (g < 5824) {
        const float* W; int O, K, ld, nt, s, l;
        if (g < 4096)      { W = f1w; O = 120; K = 256; ld = 256; nt = g >> 9; s = (g >> 6) & 7; l = g & 63; }
        else if (g < 5632) { const int f = g - 4096; W = f2w; O = 84; K = 120; ld = 120; nt = f >> 8; s = (f >> 6) & 3; l = f & 63; }
        else               { const int f = g - 5632; W = f3w; O = 10; K = 84;  ld = 84;  nt = 0; s = f >> 6; l = f & 63; }
        const int o = nt * 16 + (l & 15);
        #pragma unroll
        for (int j = 0; j < 8; ++j) {
            const int k = 32 * s + 8 * (l >> 4) + j;
            v[j] = (o < O && k < K) ? W[o * ld + k] : 0.f;
        }
    } else if (g < 6336) {
        const int f = g - 5824, s = f >> 6, l = f & 63;
        const int c = l & 15, h = l >> 4;
        #pragma unroll
        for (int jp = 0; jp < 4; ++jp) {
            const int D = 16 * s + 4 * h + jp;
            const int ky = D / 24, rem = D % 24, kx = rem >> 2, icp = rem & 3;
            const bool ok = (ky < 5 && kx < 5);
            v[2 * jp]     = (ok && 2 * icp < 6)     ? c2w[c * 150 + (2 * icp) * 25 + ky * 5 + kx]     : 0.f;
            v[2 * jp + 1] = (ok && 2 * icp + 1 < 6) ? c2w[c * 150 + (2 * icp + 1) * 25 + ky * 5 + kx] : 0.f;
        }
    } else {
        const int l = (g - 6336) & 63;
        const int c = l & 15, h = l >> 4;
        const int oc = c >> 1, xs = c & 1;
        #pragma unroll
        for (int j = 0; j < 8; ++j) {
            const int p = h * 4 + (j >> 1);
            float w = 0.f;
            if (p < 15 && c < 12) {
                const int ky = p / 3, kx = 2 * (p % 3) + (j & 1) - xs;
                if (kx >= 0 && kx < 5) w = c1w[oc * 25 + ky * 5 + kx];
            }
            v[j] = w;
        }
    }
    uint4 r;
    r.x = pk_bf16(v[0], v[1]); r.y = pk_bf16(v[2], v[3]);
    r.z = pk_bf16(v[4], v[5]); r.w = pk_bf16(v[6], v[7]);
    ws[g] = r;
}

// LDS map (39712 B -> 4 blocks/CU LDS-cap):
//  [0,12576)      imgu bf16 [8][393 dw] per pass; after convs: A2 [16][68dw]@0,
//                 A3 [16][52dw]@4352, lgf [16][12]f32 @7680
//  [12576,31264)  p1 bf16 [8][12][12][8ic] + tail (zeroed; R5 lesson); after
//                 last conv2: E1P[4ph][4be][104] @12576, E2RP @19232 (zero-pad
//                 phase-shifted copies for aligned float4 segment dots)
//  [31264,39712)  A1 bf16 [16 img][132 dw]
// __launch_bounds__ 2nd arg acts as min BLOCKS/CU on this toolchain
// (R10: (512,8)->VGPR 32, 253MB spill; R11: (512,4)->VGPR 64, 200MB spill).
// (512,3) -> 24 waves/CU -> VGPR cap ~85 >= natural ~75 -> no spill.
__global__ __launch_bounds__(512, 3) void lenet_circuit_kernel(
    const float* __restrict__ images,
    const float* __restrict__ c1b, const float* __restrict__ c2b,
    const float* __restrict__ f1b, const float* __restrict__ f2b,
    const float* __restrict__ f3b, const uint4* __restrict__ wsb,
    float* __restrict__ out)
{
    __shared__ __align__(16) unsigned char s_mem[39712];
    unsigned*       imgu = (unsigned*)s_mem;
    unsigned short* p1s  = (unsigned short*)(s_mem + 12576);
    const uint4*    p1u4 = (const uint4*)(s_mem + 12576);
    unsigned*       A1d  = (unsigned*)(s_mem + 31264);
    const uint4*    A1q  = (const uint4*)(s_mem + 31264);
    float*          E1Pf = (float*)(s_mem + 12576);   // [4ph][4be][104]
    float*          E2Rf = (float*)(s_mem + 19232);   // [4ph][4be][104]

    const int t = threadIdx.x, bid = blockIdx.x;
    const int lane = t & 63, wav = t >> 6;   // 8 waves
    const int c = lane & 15, h = lane >> 4;
    const uint4 z4 = {0u, 0u, 0u, 0u};

    // ---- zero p1 region once ----
    {
        uint4* pz = (uint4*)(s_mem + 12576);
        for (int i = t; i < 1168; i += 512) pz[i] = z4;
    }
    // ---- load weight fragments (coalesced) ----
    Frag8 a1; a1.q = wsb[6336 + lane];
    Frag8 w2[8];
    #pragma unroll
    for (int s = 0; s < 8; ++s) w2[s].q = wsb[5824 + s * 64 + lane];
    int koff[8];
    #pragma unroll
    for (int s = 0; s < 8; ++s) {
        const int D0 = 16 * s + 4 * h;
        koff[s] = (D0 / 24) * 12 + ((D0 % 24) >> 2);
    }
    int pd[4];
    #pragma unroll
    for (int q = 0; q < 4; ++q) {
        const int p = 4 * h + q;
        pd[q] = (p < 15) ? (p / 3) * 14 + (p % 3) : 0;
    }
    float bias0 = 0.f, bias1 = 0.f;
    if (h < 3) { bias0 = c1b[2 * h]; bias1 = c1b[2 * h + 1]; }
    const float b2v = c2b[c];

    // ================= two conv passes (8 images each) =================
    for (int pass = 0; pass < 2; ++pass) {
        // ---- stage 8 images fp32 -> bf16 ----
        {
            const float4* g = (const float4*)(images + (size_t)bid * 12544 + pass * 6272);
            for (int i = t; i < 1568; i += 512) {
                const float4 v = g[i];
                const int im = i / 196, j = i % 196;
                imgu[im * 393 + 2 * j]     = pk_bf16(v.x, v.y);
                imgu[im * 393 + 2 * j + 1] = pk_bf16(v.z, v.w);
            }
        }
        __syncthreads();

        // ---- conv1: 18 MFMA-tasks per wave ----
        {
            const int n = c, img = n >> 1;
            const int imb = img * 393 + (n & 1) * 14;
            for (int task = wav * 18; task < wav * 18 + 18; ++task) {
                const int qy = task / 12, qx = task % 12;
                const int base = imb + qy * 28 + qx;
                Frag8 bf;
                #pragma unroll
                for (int q = 0; q < 4; ++q) bf.u[q] = imgu[base + pd[q]];
                float4v acc = {0.f, 0.f, 0.f, 0.f};
                acc = __builtin_amdgcn_mfma_f32_16x16x32_bf16(a1.v, bf.v, acc, 0, 0, 0);
                float v0 = fmaxf(acc[0], acc[1]);
                float v1 = fmaxf(acc[2], acc[3]);
                v0 = fmaxf(v0, __shfl_xor(v0, 1));
                v1 = fmaxf(v1, __shfl_xor(v1, 1));
                if ((n & 1) == 0 && h < 3) {
                    const unsigned pkv = pk_bf16(fmaxf(v0 + bias0, 0.f),
                                                 fmaxf(v1 + bias1, 0.f));
                    *(unsigned*)&p1s[img * 1152 + qy * 96 + qx * 8 + 2 * h] = pkv;
                }
            }
        }
        __syncthreads();

        // ---- conv2: wave = image i0; 32 MFMA/wave ----
        {
            const int i0 = wav;
            const int pxl = (c & 1) + 2 * ((c >> 2) & 1);
            const int pyl = ((c >> 1) & 1) + 2 * ((c >> 3) & 1);
            #pragma unroll
            for (int mt = 0; mt < 4; ++mt) {
                const int px = pxl + 4 * (mt & 1), py = pyl + 4 * (mt >> 1);
                const int base = i0 * 144 + py * 12 + px;
                float4v acc = {0.f, 0.f, 0.f, 0.f};
                #pragma unroll
                for (int s = 0; s < 8; ++s) {
                    Frag8 af; af.q = p1u4[base + koff[s]];
                    acc = __builtin_amdgcn_mfma_f32_16x16x32_bf16(af.v, w2[s].v, acc, 0, 0, 0);
                }
                const float p = fmaxf(fmaxf(acc[0], acc[1]), fmaxf(acc[2], acc[3]));
                float v = fmaxf(p + b2v, 0.f);
                const float vp = __shfl_xor(v, 16);
                if ((h & 1) == 0) {
                    const int qy = (h >> 1) + 2 * (mt >> 1);
                    A1d[(pass * 8 + i0) * 132 + c * 8 + qy * 2 + (mt & 1)] = pk_bf16(v, vp);
                }
            }
        }
    }
    __syncthreads();   // A1 complete; p1 dead

    // ---- fc1 via MFMA (nt = wav, 8 MFMA/wave) + zero phase region ----
    {
        uint4* pz = (uint4*)(s_mem + 12576);        // zero E1P+E2RP (13312 B)
        for (int i = t; i < 832; i += 512) pz[i] = z4;
        unsigned* A2d = (unsigned*)s_mem;
        if (t < 64) A2d[(t >> 2) * 68 + 60 + (t & 3)] = 0u;   // k-pad 120-127
        float4v acc = {0.f, 0.f, 0.f, 0.f};
        #pragma unroll
        for (int s = 0; s < 8; ++s) {
            Frag8 af; af.q = A1q[c * 33 + 4 * s + h];
            Frag8 b; b.q = wsb[(wav * 8 + s) * 64 + lane];
            acc = __builtin_amdgcn_mfma_f32_16x16x32_bf16(af.v, b.v, acc, 0, 0, 0);
        }
        const int o = 16 * wav + c;
        const float bias = (o < 120) ? f1b[o] : 0.f;
        #pragma unroll
        for (int r = 0; r < 4; ++r) {
            float v = fmaxf(acc[r] + bias, 0.f);
            const float vp = __shfl_xor(v, 1);
            if ((c & 1) == 0 && o < 120)
                A2d[(4 * h + r) * 68 + (o >> 1)] = pk_bf16(v, vp);
        }
    }
    __syncthreads();

    // ---- fc2 via MFMA (waves 0-5, 4 MFMA each) ----
    {
        unsigned* A3d = (unsigned*)(s_mem + 4352);
        if (t < 96) A3d[(t / 6) * 52 + 42 + (t % 6)] = 0u;    // k-pad 84-95
        if (wav < 6) {
            const uint4* A2q = (const uint4*)s_mem;
            float4v acc = {0.f, 0.f, 0.f, 0.f};
            #pragma unroll
            for (int s = 0; s < 4; ++s) {
                Frag8 af; af.q = A2q[c * 17 + 4 * s + h];
                Frag8 b; b.q = wsb[4096 + (wav * 4 + s) * 64 + lane];
                acc = __builtin_amdgcn_mfma_f32_16x16x32_bf16(af.v, b.v, acc, 0, 0, 0);
            }
            const int o = 16 * wav + c;
            const float bias = (o < 84) ? f2b[o] : 0.f;
            #pragma unroll
            for (int r = 0; r < 4; ++r) {
                float v = fmaxf(acc[r] + bias, 0.f);
                const float vp = __shfl_xor(v, 1);
                if ((c & 1) == 0 && o < 84)
                    A3d[(4 * h + r) * 52 + (o >> 1)] = pk_bf16(v, vp);
            }
        }
    }
    __syncthreads();

    float* lgf = (float*)(s_mem + 7680);    // [16][12]

    // ---- fc3 via MFMA (wave 0) ----
    if (wav == 0) {
        const uint4* A3q = (const uint4*)(s_mem + 4352);
        float4v acc = {0.f, 0.f, 0.f, 0.f};
        #pragma unroll
        for (int s = 0; s < 3; ++s) {
            Frag8 af; af.q = A3q[c * 13 + 4 * s + h];
            Frag8 b; b.q = wsb[5632 + s * 64 + lane];
            acc = __builtin_amdgcn_mfma_f32_16x16x32_bf16(af.v, b.v, acc, 0, 0, 0);
        }
        if (c < 10) {
            const float bias = f3b[c];
            #pragma unroll
            for (int r = 0; r < 4; ++r) lgf[(4 * h + r) * 12 + c] = acc[r] + bias;
        }
    }
    __syncthreads();

    // ---- log_softmax per image (16) ----
    if (t < 16) {
        float* lp = lgf + t * 12;
        float mx = -INFINITY;
        #pragma unroll
        for (int i = 0; i < 10; ++i) mx = fmaxf(mx, lp[i]);
        float sum = 0.f;
        #pragma unroll
        for (int i = 0; i < 10; ++i) sum += expf(lp[i] - mx);
        const float lse = mx + logf(sum);
        #pragma unroll
        for (int i = 0; i < 10; ++i) lp[i] -= lse;
    }
    __syncthreads();

    // ---- per-number probs -> 4 phase-shifted copies (E2 stored reversed) ----
    for (int idx = t; idx < 800; idx += 512) {
        const int be = idx / 200, r = idx % 200;
        const float* lp = lgf + 4 * be * 12;
        if (r < 100) {
            const float v = expf(lp[r / 10] + lp[12 + r % 10]);
            #pragma unroll
            for (int ph = 0; ph < 4; ++ph)
                E1Pf[(ph * 4 + be) * 104 + r + ph] = v;
        } else {
            const int k = r - 100;
            const float v = expf(lp[24 + k / 10] + lp[36 + k % 10]);
            #pragma unroll
            for (int ph = 0; ph < 4; ++ph)
                E2Rf[(ph * 4 + be) * 104 + (99 - k) + ph] = v;
        }
    }
    __syncthreads();

    // ---- segments: thread t<400 owns pair (sp, sp+99); aligned float4 dots ----
    if (t < 400) {
        const int be = t / 100, sp = t % 100;
        float* ob = out + ((size_t)bid * 4 + be) * SUMS;
        #pragma unroll
        for (int form = 0; form < 2; ++form) {
            const int o1 = form ? sp : 0;
            const int o2 = form ? 0 : 99 - sp;
            const int len = form ? 100 - sp : sp + 1;
            if (form && sp == 0) break;
            const int ph1 = (4 - (o1 & 3)) & 3, ph2 = (4 - (o2 & 3)) & 3;
            const float4* P1 = (const float4*)(E1Pf + (ph1 * 4 + be) * 104) + ((o1 + ph1) >> 2);
            const float4* P2 = (const float4*)(E2Rf + (ph2 * 4 + be) * 104) + ((o2 + ph2) >> 2);
            const int nv = (len + 3) >> 2;
            float s = 0.f;
            for (int j = 0; j < nv; ++j) {
                const float4 a = P1[j], b = P2[j];
                s += a.x * b.x + a.y * b.y + a.z * b.z + a.w * b.w;
            }
            ob[form ? sp + 99 : sp] = logf(s);
        }
    }
}

extern "C" void kernel_launch(void* const* d_in, const int* in_sizes, int n_in,
                              void* d_out, int out_size, void* d_ws, size_t ws_size,
                              hipStream_t stream) {
    const float* images = (const float*)d_in[0];
    const float* c1w = (const float*)d_in[1];
    const float* c1b = (const float*)d_in[2];
    const float* c2w = (const float*)d_in[3];
    const float* c2b = (const float*)d_in[4];
    const float* f1w = (const float*)d_in[5];
    const float* f1b = (const float*)d_in[6];
    const float* f2w = (const float*)d_in[7];
    const float* f2b = (const float*)d_in[8];
    const float* f3w = (const float*)d_in[9];
    const float* f3b = (const float*)d_in[10];
    float* out = (float*)d_out;

    convert_weights<<<25, 256, 0, stream>>>(f1w, f2w, f3w, c1w, c2w, (uint4*)d_ws);
    lenet_circuit_kernel<<<NBLK, 512, 0, stream>>>(
        images, c1b, c2b, f1b, f2b, f3b, (const uint4*)d_ws, out);
}

// Round 13
// 146.170 us; speedup vs baseline: 1.7790x; 1.2046x over previous
//
#include <hip/hip_runtime.h>
#include <hip/hip_bf16.h>
#include <math.h>

#define SUMS 199
#define NBLK 1024   // 16 images = 4 batch elements per block, 256 threads (R9 config)

typedef __attribute__((ext_vector_type(8))) short short8;   // 8 bf16
typedef __attribute__((ext_vector_type(4))) float float4v;  // MFMA acc

union Frag8 { short8 v; unsigned u[4]; uint4 q; };

static __device__ inline unsigned pk_bf16(float a, float b) {
    __hip_bfloat162 h = __float22bfloat162_rn(make_float2(a, b));
    union { __hip_bfloat162 h; unsigned u; } c; c.h = h; return c.u;
}

// ---- pre-kernel: all weight fragments -> d_ws (bf16 frag layout) ----
__global__ __launch_bounds__(256) void convert_weights(
    const float* __restrict__ f1w, const float* __restrict__ f2w,
    const float* __restrict__ f3w, const float* __restrict__ c1w,
    const float* __restrict__ c2w, uint4* __restrict__ ws)
{
    const int g = blockIdx.x * 256 + threadIdx.x;
    if (g >= 6400) return;
    float v[8];
    if (g < 5824) {
        const float* W; int O, K, ld, nt, s, l;
        if (g < 4096)      { W = f1w; O = 120; K = 256; ld = 256; nt = g >> 9; s = (g >> 6) & 7; l = g & 63; }
        else if (g < 5632) { const int f = g - 4096; W = f2w; O = 84; K = 120; ld = 120; nt = f >> 8; s = (f >> 6) & 3; l = f & 63; }
        else               { const int f = g - 5632; W = f3w; O = 10; K = 84;  ld = 84;  nt = 0; s = f >> 6; l = f & 63; }
        const int o = nt * 16 + (l & 15);
        #pragma unroll
        for (int j = 0; j < 8; ++j) {
            const int k = 32 * s + 8 * (l >> 4) + j;
            v[j] = (o < O && k < K) ? W[o * ld + k] : 0.f;
        }
    } else if (g < 6336) {
        const int f = g - 5824, s = f >> 6, l = f & 63;
        const int c = l & 15, h = l >> 4;
        #pragma unroll
        for (int jp = 0; jp < 4; ++jp) {
            const int D = 16 * s + 4 * h + jp;
            const int ky = D / 24, rem = D % 24, kx = rem >> 2, icp = rem & 3;
            const bool ok = (ky < 5 && kx < 5);
            v[2 * jp]     = (ok && 2 * icp < 6)     ? c2w[c * 150 + (2 * icp) * 25 + ky * 5 + kx]     : 0.f;
            v[2 * jp + 1] = (ok && 2 * icp + 1 < 6) ? c2w[c * 150 + (2 * icp + 1) * 25 + ky * 5 + kx] : 0.f;
        }
    } else {
        const int l = (g - 6336) & 63;
        const int c = l & 15, h = l >> 4;
        const int oc = c >> 1, xs = c & 1;
        #pragma unroll
        for (int j = 0; j < 8; ++j) {
            const int p = h * 4 + (j >> 1);
            float w = 0.f;
            if (p < 15 && c < 12) {
                const int ky = p / 3, kx = 2 * (p % 3) + (j & 1) - xs;
                if (kx >= 0 && kx < 5) w = c1w[oc * 25 + ky * 5 + kx];
            }
            v[j] = w;
        }
    }
    uint4 r;
    r.x = pk_bf16(v[0], v[1]); r.y = pk_bf16(v[2], v[3]);
    r.z = pk_bf16(v[4], v[5]); r.w = pk_bf16(v[6], v[7]);
    ws[g] = r;
}

// LDS map (39712 B -> 4 blocks/CU, grid fully resident @ 1024 blocks):
//  [0,12576)      imgu bf16 [8][393 dw] per pass; after convs: A2 [16][68dw]@0,
//                 A3 [16][52dw]@4352, lgf [16][12]f32 @7680
//  [12576,31264)  p1 bf16 [8][12][12][8ic] + tail (zeroed; R5 lesson); after
//                 last conv2: E1P[4ph][4be][104] @12576, E2RP @19232 (zero-pad
//                 phase-shifted copies for aligned float4 segment dots)
//  [31264,39712)  A1 bf16 [16 img][132 dw]
// 256-thread / 4-wave blocks: R12 showed 512-thr + more waves/CU loses
// (VGPR cap vs spill vs block-tail); this config is fully resident, no spill.
__global__ __launch_bounds__(256) void lenet_circuit_kernel(
    const float* __restrict__ images,
    const float* __restrict__ c1b, const float* __restrict__ c2b,
    const float* __restrict__ f1b, const float* __restrict__ f2b,
    const float* __restrict__ f3b, const uint4* __restrict__ wsb,
    float* __restrict__ out)
{
    __shared__ __align__(16) unsigned char s_mem[39712];
    unsigned*       imgu = (unsigned*)s_mem;
    unsigned short* p1s  = (unsigned short*)(s_mem + 12576);
    const uint4*    p1u4 = (const uint4*)(s_mem + 12576);
    unsigned*       A1d  = (unsigned*)(s_mem + 31264);
    const uint4*    A1q  = (const uint4*)(s_mem + 31264);
    float*          E1Pf = (float*)(s_mem + 12576);   // [4ph][4be][104]
    float*          E2Rf = (float*)(s_mem + 19232);   // [4ph][4be][104]

    const int t = threadIdx.x, bid = blockIdx.x;
    const int lane = t & 63, wav = t >> 6;   // 4 waves
    const int c = lane & 15, h = lane >> 4;
    const uint4 z4 = {0u, 0u, 0u, 0u};

    // ---- zero p1 region once ----
    {
        uint4* pz = (uint4*)(s_mem + 12576);
        for (int i = t; i < 1168; i += 256) pz[i] = z4;
    }
    // ---- load weight fragments (coalesced) ----
    Frag8 a1; a1.q = wsb[6336 + lane];
    Frag8 w2[8];
    #pragma unroll
    for (int s = 0; s < 8; ++s) w2[s].q = wsb[5824 + s * 64 + lane];
    int koff[8];
    #pragma unroll
    for (int s = 0; s < 8; ++s) {
        const int D0 = 16 * s + 4 * h;
        koff[s] = (D0 / 24) * 12 + ((D0 % 24) >> 2);
    }
    int pd[4];
    #pragma unroll
    for (int q = 0; q < 4; ++q) {
        const int p = 4 * h + q;
        pd[q] = (p < 15) ? (p / 3) * 14 + (p % 3) : 0;
    }
    float bias0 = 0.f, bias1 = 0.f;
    if (h < 3) { bias0 = c1b[2 * h]; bias1 = c1b[2 * h + 1]; }
    const float b2v = c2b[c];

    // ================= two conv passes (8 images each) =================
    for (int pass = 0; pass < 2; ++pass) {
        // ---- stage 8 images fp32 -> bf16 ----
        {
            const float4* g = (const float4*)(images + (size_t)bid * 12544 + pass * 6272);
            for (int i = t; i < 1568; i += 256) {
                const float4 v = g[i];
                const int im = i / 196, j = i % 196;
                imgu[im * 393 + 2 * j]     = pk_bf16(v.x, v.y);
                imgu[im * 393 + 2 * j + 1] = pk_bf16(v.z, v.w);
            }
        }
        __syncthreads();

        // ---- conv1: 36 MFMA-tasks per wave ----
        {
            const int n = c, img = n >> 1;
            const int imb = img * 393 + (n & 1) * 14;
            for (int qy = wav * 3; qy < wav * 3 + 3; ++qy) {
                #pragma unroll
                for (int qx = 0; qx < 12; ++qx) {
                    const int base = imb + qy * 28 + qx;
                    Frag8 bf;
                    #pragma unroll
                    for (int q = 0; q < 4; ++q) bf.u[q] = imgu[base + pd[q]];
                    float4v acc = {0.f, 0.f, 0.f, 0.f};
                    acc = __builtin_amdgcn_mfma_f32_16x16x32_bf16(a1.v, bf.v, acc, 0, 0, 0);
                    float v0 = fmaxf(acc[0], acc[1]);
                    float v1 = fmaxf(acc[2], acc[3]);
                    v0 = fmaxf(v0, __shfl_xor(v0, 1));
                    v1 = fmaxf(v1, __shfl_xor(v1, 1));
                    if ((n & 1) == 0 && h < 3) {
                        const unsigned pkv = pk_bf16(fmaxf(v0 + bias0, 0.f),
                                                     fmaxf(v1 + bias1, 0.f));
                        *(unsigned*)&p1s[img * 1152 + qy * 96 + qx * 8 + 2 * h] = pkv;
                    }
                }
            }
        }
        __syncthreads();

        // ---- conv2: wave = 2 images; 64 MFMA/wave; writes A1 rows ----
        {
            const int pxl = (c & 1) + 2 * ((c >> 2) & 1);
            const int pyl = ((c >> 1) & 1) + 2 * ((c >> 3) & 1);
            #pragma unroll
            for (int ii = 0; ii < 2; ++ii) {
                const int i0 = 2 * wav + ii;
                #pragma unroll
                for (int mt = 0; mt < 4; ++mt) {
                    const int px = pxl + 4 * (mt & 1), py = pyl + 4 * (mt >> 1);
                    const int base = i0 * 144 + py * 12 + px;
                    float4v acc = {0.f, 0.f, 0.f, 0.f};
                    #pragma unroll
                    for (int s = 0; s < 8; ++s) {
                        Frag8 af; af.q = p1u4[base + koff[s]];
                        acc = __builtin_amdgcn_mfma_f32_16x16x32_bf16(af.v, w2[s].v, acc, 0, 0, 0);
                    }
                    const float p = fmaxf(fmaxf(acc[0], acc[1]), fmaxf(acc[2], acc[3]));
                    float v = fmaxf(p + b2v, 0.f);
                    const float vp = __shfl_xor(v, 16);
                    if ((h & 1) == 0) {
                        const int qy = (h >> 1) + 2 * (mt >> 1);
                        A1d[(pass * 8 + i0) * 132 + c * 8 + qy * 2 + (mt & 1)] = pk_bf16(v, vp);
                    }
                }
            }
        }
        // no barrier: next-pass staging touches only imgu; its barrier orders p1
    }
    __syncthreads();   // A1 complete; p1 dead

    // ---- fc1 via MFMA (2 n-tiles/wave, 16 MFMA) + zero phase region ----
    {
        uint4* pz = (uint4*)(s_mem + 12576);        // zero E1P+E2RP (13312 B)
        for (int i = t; i < 832; i += 256) pz[i] = z4;
        unsigned* A2d = (unsigned*)s_mem;
        if (t < 64) A2d[(t >> 2) * 68 + 60 + (t & 3)] = 0u;   // k-pad 120-127
        float4v acc0 = {0.f, 0.f, 0.f, 0.f}, acc1 = acc0;
        const int nt0 = 2 * wav;
        #pragma unroll
        for (int s = 0; s < 8; ++s) {
            Frag8 af; af.q = A1q[c * 33 + 4 * s + h];
            Frag8 b0; b0.q = wsb[(nt0 * 8 + s) * 64 + lane];
            Frag8 b1; b1.q = wsb[((nt0 + 1) * 8 + s) * 64 + lane];
            acc0 = __builtin_amdgcn_mfma_f32_16x16x32_bf16(af.v, b0.v, acc0, 0, 0, 0);
            acc1 = __builtin_amdgcn_mfma_f32_16x16x32_bf16(af.v, b1.v, acc1, 0, 0, 0);
        }
        #pragma unroll
        for (int ntl = 0; ntl < 2; ++ntl) {
            const int o = 32 * wav + 16 * ntl + c;
            const float bias = (o < 120) ? f1b[o] : 0.f;
            #pragma unroll
            for (int r = 0; r < 4; ++r) {
                float v = fmaxf((ntl ? acc1[r] : acc0[r]) + bias, 0.f);
                const float vp = __shfl_xor(v, 1);
                if ((c & 1) == 0 && o < 120)
                    A2d[(4 * h + r) * 68 + (o >> 1)] = pk_bf16(v, vp);
            }
        }
    }
    __syncthreads();

    // ---- fc2 via MFMA (waves 0-2, 2 n-tiles each) ----
    {
        unsigned* A3d = (unsigned*)(s_mem + 4352);
        if (t < 96) A3d[(t / 6) * 52 + 42 + (t % 6)] = 0u;    // k-pad 84-95
        if (wav < 3) {
            const uint4* A2q = (const uint4*)s_mem;
            float4v acc0 = {0.f, 0.f, 0.f, 0.f}, acc1 = acc0;
            const int nt0 = 2 * wav;
            #pragma unroll
            for (int s = 0; s < 4; ++s) {
                Frag8 af; af.q = A2q[c * 17 + 4 * s + h];
                Frag8 b0; b0.q = wsb[4096 + (nt0 * 4 + s) * 64 + lane];
                Frag8 b1; b1.q = wsb[4096 + ((nt0 + 1) * 4 + s) * 64 + lane];
                acc0 = __builtin_amdgcn_mfma_f32_16x16x32_bf16(af.v, b0.v, acc0, 0, 0, 0);
                acc1 = __builtin_amdgcn_mfma_f32_16x16x32_bf16(af.v, b1.v, acc1, 0, 0, 0);
            }
            #pragma unroll
            for (int ntl = 0; ntl < 2; ++ntl) {
                const int o = 32 * wav + 16 * ntl + c;
                const float bias = (o < 84) ? f2b[o] : 0.f;
                #pragma unroll
                for (int r = 0; r < 4; ++r) {
                    float v = fmaxf((ntl ? acc1[r] : acc0[r]) + bias, 0.f);
                    const float vp = __shfl_xor(v, 1);
                    if ((c & 1) == 0 && o < 84)
                        A3d[(4 * h + r) * 52 + (o >> 1)] = pk_bf16(v, vp);
                }
            }
        }
    }
    __syncthreads();

    float* lgf = (float*)(s_mem + 7680);    // [16][12] log-probs

    // ---- fc3 via MFMA (wave 0) with FUSED log_softmax (shfl butterfly over
    //      class lanes c=0..15; classes 10-15 masked to -inf / 0) ----
    if (wav == 0) {
        const uint4* A3q = (const uint4*)(s_mem + 4352);
        float4v acc = {0.f, 0.f, 0.f, 0.f};
        #pragma unroll
        for (int s = 0; s < 3; ++s) {
            Frag8 af; af.q = A3q[c * 13 + 4 * s + h];
            Frag8 b; b.q = wsb[5632 + s * 64 + lane];
            acc = __builtin_amdgcn_mfma_f32_16x16x32_bf16(af.v, b.v, acc, 0, 0, 0);
        }
        const float bias = (c < 10) ? f3b[c] : 0.f;
        float x[4], m[4], sm[4];
        #pragma unroll
        for (int r = 0; r < 4; ++r) {
            x[r] = (c < 10) ? (acc[r] + bias) : -INFINITY;
            m[r] = x[r];
        }
        #pragma unroll
        for (int d = 1; d <= 8; d <<= 1)
            #pragma unroll
            for (int r = 0; r < 4; ++r) m[r] = fmaxf(m[r], __shfl_xor(m[r], d));
        #pragma unroll
        for (int r = 0; r < 4; ++r) sm[r] = (c < 10) ? expf(x[r] - m[r]) : 0.f;
        #pragma unroll
        for (int d = 1; d <= 8; d <<= 1)
            #pragma unroll
            for (int r = 0; r < 4; ++r) sm[r] += __shfl_xor(sm[r], d);
        if (c < 10) {
            #pragma unroll
            for (int r = 0; r < 4; ++r)
                lgf[(4 * h + r) * 12 + c] = x[r] - (m[r] + logf(sm[r]));
        }
    }
    __syncthreads();

    // ---- per-number probs -> 4 phase-shifted copies (E2 stored reversed) ----
    for (int idx = t; idx < 800; idx += 256) {
        const int be = idx / 200, r = idx % 200;
        const float* lp = lgf + 4 * be * 12;
        if (r < 100) {
            const float v = expf(lp[r / 10] + lp[12 + r % 10]);
            #pragma unroll
            for (int ph = 0; ph < 4; ++ph)
                E1Pf[(ph * 4 + be) * 104 + r + ph] = v;
        } else {
            const int k = r - 100;
            const float v = expf(lp[24 + k / 10] + lp[36 + k % 10]);
            #pragma unroll
            for (int ph = 0; ph < 4; ++ph)
                E2Rf[(ph * 4 + be) * 104 + (99 - k) + ph] = v;
        }
    }
    __syncthreads();

    // ---- segments: pair (sp, sp+99) per pid; aligned float4 dots ----
    for (int pid = t; pid < 400; pid += 256) {
        const int be = pid / 100, sp = pid % 100;
        float* ob = out + ((size_t)bid * 4 + be) * SUMS;
        #pragma unroll
        for (int form = 0; form < 2; ++form) {
            const int o1 = form ? sp : 0;
            const int o2 = form ? 0 : 99 - sp;
            const int len = form ? 100 - sp : sp + 1;
            if (form && sp == 0) break;
            const int ph1 = (4 - (o1 & 3)) & 3, ph2 = (4 - (o2 & 3)) & 3;
            const float4* P1 = (const float4*)(E1Pf + (ph1 * 4 + be) * 104) + ((o1 + ph1) >> 2);
            const float4* P2 = (const float4*)(E2Rf + (ph2 * 4 + be) * 104) + ((o2 + ph2) >> 2);
            const int nv = (len + 3) >> 2;
            float s = 0.f;
            for (int j = 0; j < nv; ++j) {
                const float4 a = P1[j], b = P2[j];
                s += a.x * b.x + a.y * b.y + a.z * b.z + a.w * b.w;
            }
            ob[form ? sp + 99 : sp] = logf(s);
        }
    }
}

extern "C" void kernel_launch(void* const* d_in, const int* in_sizes, int n_in,
                              void* d_out, int out_size, void* d_ws, size_t ws_size,
                              hipStream_t stream) {
    const float* images = (const float*)d_in[0];
    const float* c1w = (const float*)d_in[1];
    const float* c1b = (const float*)d_in[2];
    const float* c2w = (const float*)d_in[3];
    const float* c2b = (const float*)d_in[4];
    const float* f1w = (const float*)d_in[5];
    const float* f1b = (const float*)d_in[6];
    const float* f2w = (const float*)d_in[7];
    const float* f2b = (const float*)d_in[8];
    const float* f3w = (const float*)d_in[9];
    const float* f3b = (const float*)d_in[10];
    float* out = (float*)d_out;

    convert_weights<<<25, 256, 0, stream>>>(f1w, f2w, f3w, c1w, c2w, (uint4*)d_ws);
    lenet_circuit_kernel<<<NBLK, 256, 0, stream>>>(
        images, c1b, c2b, f1b, f2b, f3b, (const uint4*)d_ws, out);
}

// Round 14
// 139.611 us; speedup vs baseline: 1.8625x; 1.0470x over previous
//
#include <hip/hip_runtime.h>
#include <hip/hip_bf16.h>
#include <math.h>

#define SUMS 199
#define NBLK 1024   // 16 images = 4 batch elements per block, 256 threads

typedef __attribute__((ext_vector_type(8))) short short8;   // 8 bf16
typedef __attribute__((ext_vector_type(4))) float float4v;  // MFMA acc

union Frag8 { short8 v; unsigned u[4]; uint4 q; };

static __device__ inline unsigned pk_bf16(float a, float b) {
    __hip_bfloat162 h = __float22bfloat162_rn(make_float2(a, b));
    union { __hip_bfloat162 h; unsigned u; } c; c.h = h; return c.u;
}

// ---- pre-kernel: all weight fragments -> d_ws (bf16 frag layout) ----
__global__ __launch_bounds__(256) void convert_weights(
    const float* __restrict__ f1w, const float* __restrict__ f2w,
    const float* __restrict__ f3w, const float* __restrict__ c1w,
    const float* __restrict__ c2w, uint4* __restrict__ ws)
{
    const int g = blockIdx.x * 256 + threadIdx.x;
    if (g >= 6400) return;
    float v[8];
    if (g < 5824) {
        const float* W; int O, K, ld, nt, s, l;
        if (g < 4096)      { W = f1w; O = 120; K = 256; ld = 256; nt = g >> 9; s = (g >> 6) & 7; l = g & 63; }
        else if (g < 5632) { const int f = g - 4096; W = f2w; O = 84; K = 120; ld = 120; nt = f >> 8; s = (f >> 6) & 3; l = f & 63; }
        else               { const int f = g - 5632; W = f3w; O = 10; K = 84;  ld = 84;  nt = 0; s = f >> 6; l = f & 63; }
        const int o = nt * 16 + (l & 15);
        #pragma unroll
        for (int j = 0; j < 8; ++j) {
            const int k = 32 * s + 8 * (l >> 4) + j;
            v[j] = (o < O && k < K) ? W[o * ld + k] : 0.f;
        }
    } else if (g < 6336) {
        const int f = g - 5824, s = f >> 6, l = f & 63;
        const int c = l & 15, h = l >> 4;
        #pragma unroll
        for (int jp = 0; jp < 4; ++jp) {
            const int D = 16 * s + 4 * h + jp;
            const int ky = D / 24, rem = D % 24, kx = rem >> 2, icp = rem & 3;
            const bool ok = (ky < 5 && kx < 5);
            v[2 * jp]     = (ok && 2 * icp < 6)     ? c2w[c * 150 + (2 * icp) * 25 + ky * 5 + kx]     : 0.f;
            v[2 * jp + 1] = (ok && 2 * icp + 1 < 6) ? c2w[c * 150 + (2 * icp + 1) * 25 + ky * 5 + kx] : 0.f;
        }
    } else {
        const int l = (g - 6336) & 63;
        const int c = l & 15, h = l >> 4;
        const int oc = c >> 1, xs = c & 1;
        #pragma unroll
        for (int j = 0; j < 8; ++j) {
            const int p = h * 4 + (j >> 1);
            float w = 0.f;
            if (p < 15 && c < 12) {
                const int ky = p / 3, kx = 2 * (p % 3) + (j & 1) - xs;
                if (kx >= 0 && kx < 5) w = c1w[oc * 25 + ky * 5 + kx];
            }
            v[j] = w;
        }
    }
    uint4 r;
    r.x = pk_bf16(v[0], v[1]); r.y = pk_bf16(v[2], v[3]);
    r.z = pk_bf16(v[4], v[5]); r.w = pk_bf16(v[6], v[7]);
    ws[g] = r;
}

// LDS map (39712 B -> 4 blocks/CU, grid fully resident @ 1024 blocks):
//  [0,12576)      imgu bf16 [8][393 dw] per pass; after convs: A2 [16][68dw]@0,
//                 A3 [16][52dw]@4352, pgf [16][12]f32 @7680 (class PROBS),
//                 Hf/Lf [4][20]f32 @8448/@8768 (digit-sum convolutions)
//  [12576,31264)  p1 bf16 [8][12][12][8ic] + tail (zeroed; R5 lesson)
//  [31264,39712)  A1 bf16 [16 img][132 dw]
// Circuit factorization (exact regroup): n1+n2 = 10(h1+h2)+(l1+l2) =>
// P_sum = (ptens1 (*) ptens2) outer-convolved with (pones1 (*) pones2):
// H,L are 19-long convs; each of the 199 outputs needs <=2 H[b]*L[a] terms.
__global__ __launch_bounds__(256) void lenet_circuit_kernel(
    const float* __restrict__ images,
    const float* __restrict__ c1b, const float* __restrict__ c2b,
    const float* __restrict__ f1b, const float* __restrict__ f2b,
    const float* __restrict__ f3b, const uint4* __restrict__ wsb,
    float* __restrict__ out)
{
    __shared__ __align__(16) unsigned char s_mem[39712];
    unsigned*       imgu = (unsigned*)s_mem;
    unsigned short* p1s  = (unsigned short*)(s_mem + 12576);
    const uint4*    p1u4 = (const uint4*)(s_mem + 12576);
    unsigned*       A1d  = (unsigned*)(s_mem + 31264);
    const uint4*    A1q  = (const uint4*)(s_mem + 31264);
    float*          pgf  = (float*)(s_mem + 7680);    // [16][12] probs
    float*          Hf   = (float*)(s_mem + 8448);    // [4][20]
    float*          Lf   = (float*)(s_mem + 8768);    // [4][20]

    const int t = threadIdx.x, bid = blockIdx.x;
    const int lane = t & 63, wav = t >> 6;   // 4 waves
    const int c = lane & 15, h = lane >> 4;
    const uint4 z4 = {0u, 0u, 0u, 0u};

    // ---- zero p1 region once ----
    {
        uint4* pz = (uint4*)(s_mem + 12576);
        for (int i = t; i < 1168; i += 256) pz[i] = z4;
    }
    // ---- load weight fragments (coalesced) ----
    Frag8 a1; a1.q = wsb[6336 + lane];
    Frag8 w2[8];
    #pragma unroll
    for (int s = 0; s < 8; ++s) w2[s].q = wsb[5824 + s * 64 + lane];
    int koff[8];
    #pragma unroll
    for (int s = 0; s < 8; ++s) {
        const int D0 = 16 * s + 4 * h;
        koff[s] = (D0 / 24) * 12 + ((D0 % 24) >> 2);
    }
    int pd[4];
    #pragma unroll
    for (int q = 0; q < 4; ++q) {
        const int p = 4 * h + q;
        pd[q] = (p < 15) ? (p / 3) * 14 + (p % 3) : 0;
    }
    float bias0 = 0.f, bias1 = 0.f;
    if (h < 3) { bias0 = c1b[2 * h]; bias1 = c1b[2 * h + 1]; }
    const float b2v = c2b[c];

    // ================= two conv passes (8 images each) =================
    for (int pass = 0; pass < 2; ++pass) {
        // ---- stage 8 images fp32 -> bf16 ----
        {
            const float4* g = (const float4*)(images + (size_t)bid * 12544 + pass * 6272);
            for (int i = t; i < 1568; i += 256) {
                const float4 v = g[i];
                const int im = i / 196, j = i % 196;
                imgu[im * 393 + 2 * j]     = pk_bf16(v.x, v.y);
                imgu[im * 393 + 2 * j + 1] = pk_bf16(v.z, v.w);
            }
        }
        __syncthreads();

        // ---- conv1: 36 MFMA-tasks per wave ----
        {
            const int n = c, img = n >> 1;
            const int imb = img * 393 + (n & 1) * 14;
            for (int qy = wav * 3; qy < wav * 3 + 3; ++qy) {
                #pragma unroll
                for (int qx = 0; qx < 12; ++qx) {
                    const int base = imb + qy * 28 + qx;
                    Frag8 bf;
                    #pragma unroll
                    for (int q = 0; q < 4; ++q) bf.u[q] = imgu[base + pd[q]];
                    float4v acc = {0.f, 0.f, 0.f, 0.f};
                    acc = __builtin_amdgcn_mfma_f32_16x16x32_bf16(a1.v, bf.v, acc, 0, 0, 0);
                    float v0 = fmaxf(acc[0], acc[1]);
                    float v1 = fmaxf(acc[2], acc[3]);
                    v0 = fmaxf(v0, __shfl_xor(v0, 1));
                    v1 = fmaxf(v1, __shfl_xor(v1, 1));
                    if ((n & 1) == 0 && h < 3) {
                        const unsigned pkv = pk_bf16(fmaxf(v0 + bias0, 0.f),
                                                     fmaxf(v1 + bias1, 0.f));
                        *(unsigned*)&p1s[img * 1152 + qy * 96 + qx * 8 + 2 * h] = pkv;
                    }
                }
            }
        }
        __syncthreads();

        // ---- conv2: wave = 2 images; writes A1 rows ----
        {
            const int pxl = (c & 1) + 2 * ((c >> 2) & 1);
            const int pyl = ((c >> 1) & 1) + 2 * ((c >> 3) & 1);
            #pragma unroll
            for (int ii = 0; ii < 2; ++ii) {
                const int i0 = 2 * wav + ii;
                #pragma unroll
                for (int mt = 0; mt < 4; ++mt) {
                    const int px = pxl + 4 * (mt & 1), py = pyl + 4 * (mt >> 1);
                    const int base = i0 * 144 + py * 12 + px;
                    float4v acc = {0.f, 0.f, 0.f, 0.f};
                    #pragma unroll
                    for (int s = 0; s < 8; ++s) {
                        Frag8 af; af.q = p1u4[base + koff[s]];
                        acc = __builtin_amdgcn_mfma_f32_16x16x32_bf16(af.v, w2[s].v, acc, 0, 0, 0);
                    }
                    const float p = fmaxf(fmaxf(acc[0], acc[1]), fmaxf(acc[2], acc[3]));
                    float v = fmaxf(p + b2v, 0.f);
                    const float vp = __shfl_xor(v, 16);
                    if ((h & 1) == 0) {
                        const int qy = (h >> 1) + 2 * (mt >> 1);
                        A1d[(pass * 8 + i0) * 132 + c * 8 + qy * 2 + (mt & 1)] = pk_bf16(v, vp);
                    }
                }
            }
        }
        // no barrier: next-pass staging touches only imgu; its barrier orders p1
    }
    __syncthreads();   // A1 complete; p1 dead

    // ---- fc1 via MFMA (2 n-tiles/wave, 16 MFMA) ----
    {
        unsigned* A2d = (unsigned*)s_mem;
        if (t < 64) A2d[(t >> 2) * 68 + 60 + (t & 3)] = 0u;   // k-pad 120-127
        float4v acc0 = {0.f, 0.f, 0.f, 0.f}, acc1 = acc0;
        const int nt0 = 2 * wav;
        #pragma unroll
        for (int s = 0; s < 8; ++s) {
            Frag8 af; af.q = A1q[c * 33 + 4 * s + h];
            Frag8 b0; b0.q = wsb[(nt0 * 8 + s) * 64 + lane];
            Frag8 b1; b1.q = wsb[((nt0 + 1) * 8 + s) * 64 + lane];
            acc0 = __builtin_amdgcn_mfma_f32_16x16x32_bf16(af.v, b0.v, acc0, 0, 0, 0);
            acc1 = __builtin_amdgcn_mfma_f32_16x16x32_bf16(af.v, b1.v, acc1, 0, 0, 0);
        }
        #pragma unroll
        for (int ntl = 0; ntl < 2; ++ntl) {
            const int o = 32 * wav + 16 * ntl + c;
            const float bias = (o < 120) ? f1b[o] : 0.f;
            #pragma unroll
            for (int r = 0; r < 4; ++r) {
                float v = fmaxf((ntl ? acc1[r] : acc0[r]) + bias, 0.f);
                const float vp = __shfl_xor(v, 1);
                if ((c & 1) == 0 && o < 120)
                    A2d[(4 * h + r) * 68 + (o >> 1)] = pk_bf16(v, vp);
            }
        }
    }
    __syncthreads();

    // ---- fc2 via MFMA (waves 0-2, 2 n-tiles each) ----
    {
        unsigned* A3d = (unsigned*)(s_mem + 4352);
        if (t < 96) A3d[(t / 6) * 52 + 42 + (t % 6)] = 0u;    // k-pad 84-95
        if (wav < 3) {
            const uint4* A2q = (const uint4*)s_mem;
            float4v acc0 = {0.f, 0.f, 0.f, 0.f}, acc1 = acc0;
            const int nt0 = 2 * wav;
            #pragma unroll
            for (int s = 0; s < 4; ++s) {
                Frag8 af; af.q = A2q[c * 17 + 4 * s + h];
                Frag8 b0; b0.q = wsb[4096 + (nt0 * 4 + s) * 64 + lane];
                Frag8 b1; b1.q = wsb[4096 + ((nt0 + 1) * 4 + s) * 64 + lane];
                acc0 = __builtin_amdgcn_mfma_f32_16x16x32_bf16(af.v, b0.v, acc0, 0, 0, 0);
                acc1 = __builtin_amdgcn_mfma_f32_16x16x32_bf16(af.v, b1.v, acc1, 0, 0, 0);
            }
            #pragma unroll
            for (int ntl = 0; ntl < 2; ++ntl) {
                const int o = 32 * wav + 16 * ntl + c;
                const float bias = (o < 84) ? f2b[o] : 0.f;
                #pragma unroll
                for (int r = 0; r < 4; ++r) {
                    float v = fmaxf((ntl ? acc1[r] : acc0[r]) + bias, 0.f);
                    const float vp = __shfl_xor(v, 1);
                    if ((c & 1) == 0 && o < 84)
                        A3d[(4 * h + r) * 52 + (o >> 1)] = pk_bf16(v, vp);
                }
            }
        }
    }
    __syncthreads();

    // ---- fc3 via MFMA (wave 0) with fused softmax -> PROBS (shfl butterfly) ----
    if (wav == 0) {
        const uint4* A3q = (const uint4*)(s_mem + 4352);
        float4v acc = {0.f, 0.f, 0.f, 0.f};
        #pragma unroll
        for (int s = 0; s < 3; ++s) {
            Frag8 af; af.q = A3q[c * 13 + 4 * s + h];
            Frag8 b; b.q = wsb[5632 + s * 64 + lane];
            acc = __builtin_amdgcn_mfma_f32_16x16x32_bf16(af.v, b.v, acc, 0, 0, 0);
        }
        const float bias = (c < 10) ? f3b[c] : 0.f;
        float x[4], m[4], e[4], sm[4];
        #pragma unroll
        for (int r = 0; r < 4; ++r) {
            x[r] = (c < 10) ? (acc[r] + bias) : -INFINITY;
            m[r] = x[r];
        }
        #pragma unroll
        for (int d = 1; d <= 8; d <<= 1)
            #pragma unroll
            for (int r = 0; r < 4; ++r) m[r] = fmaxf(m[r], __shfl_xor(m[r], d));
        #pragma unroll
        for (int r = 0; r < 4; ++r) { e[r] = (c < 10) ? expf(x[r] - m[r]) : 0.f; sm[r] = e[r]; }
        #pragma unroll
        for (int d = 1; d <= 8; d <<= 1)
            #pragma unroll
            for (int r = 0; r < 4; ++r) sm[r] += __shfl_xor(sm[r], d);
        if (c < 10) {
            #pragma unroll
            for (int r = 0; r < 4; ++r)
                pgf[(4 * h + r) * 12 + c] = e[r] / sm[r];
        }
    }
    __syncthreads();

    // ---- digit-sum convolutions: H = ptens1 (*) ptens2, L = pones1 (*) pones2 ----
    if (t < 152) {
        const int be = t / 38, j = t % 38;
        const int isH = (j < 19), b = isH ? j : j - 19;
        const float* pg = pgf + 4 * be * 12;
        const float* PA = pg + (isH ? 0 : 12);    // img 4be+0 / 4be+1
        const float* PB = pg + (isH ? 24 : 36);   // img 4be+2 / 4be+3
        const int ilo = (b > 9) ? b - 9 : 0;
        const int ihi = (b < 9) ? b : 9;
        float s = 0.f;
        for (int i = ilo; i <= ihi; ++i) s += PA[i] * PB[b - i];
        (isH ? Hf : Lf)[be * 20 + b] = s;
    }
    __syncthreads();

    // ---- outputs: P_sum(s) = sum_{10b+a=s, a,b in [0,18]} H[b]*L[a] (<=2 terms) ----
    for (int idx = t; idx < 4 * SUMS; idx += 256) {
        const int be = idx / SUMS, s = idx % SUMS;
        const float* H = Hf + be * 20;
        const float* L = Lf + be * 20;
        const int bmin = (s > 18) ? (s - 9) / 10 : 0;
        int bmax = s / 10; if (bmax > 18) bmax = 18;
        float sum = 0.f;
        for (int b = bmin; b <= bmax; ++b) sum += H[b] * L[s - 10 * b];
        out[((size_t)bid * 4 + be) * SUMS + s] = logf(sum);
    }
}

extern "C" void kernel_launch(void* const* d_in, const int* in_sizes, int n_in,
                              void* d_out, int out_size, void* d_ws, size_t ws_size,
                              hipStream_t stream) {
    const float* images = (const float*)d_in[0];
    const float* c1w = (const float*)d_in[1];
    const float* c1b = (const float*)d_in[2];
    const float* c2w = (const float*)d_in[3];
    const float* c2b = (const float*)d_in[4];
    const float* f1w = (const float*)d_in[5];
    const float* f1b = (const float*)d_in[6];
    const float* f2w = (const float*)d_in[7];
    const float* f2b = (const float*)d_in[8];
    const float* f3w = (const float*)d_in[9];
    const float* f3b = (const float*)d_in[10];
    float* out = (float*)d_out;

    convert_weights<<<25, 256, 0, stream>>>(f1w, f2w, f3w, c1w, c2w, (uint4*)d_ws);
    lenet_circuit_kernel<<<NBLK, 256, 0, stream>>>(
        images, c1b, c2b, f1b, f2b, f3b, (const uint4*)d_ws, out);
}